// Round 6
// baseline (875.629 us; speedup 1.0000x reference)
//
#include <hip/hip_runtime.h>

// WindowAttention3D: x(256,343,384) -> qkv -> per-(b,h) softmax attention (+rel bias) -> proj
// bf16 MFMA, fp32 accum. QKV GEMM writes head-major q/k/v[h][b*343+i][32] so attention
// reads are contiguous; K staged fragment-packed in LDS via global_load_lds; S^T = K*Q^T
// so P exits QK in the A-fragment layout of mfma_16x16x16 for PV (no transpose).
// R1: K must stay in LDS (global K -> vmcnt on QK chain regression).
// R2: duration invariant to wave count -> bias path was the limiter, not occupancy.
// R3: rolling-buffer dynamic index -> scratch spill (rule #20). R4: named double-buffer
//     pipelined bias: 213 -> 168us, VALU-bound.
// R5: FAILED (NaN) -- isolated to the v_cvt_pk_bf16_f32 inline asm (likely partial/opsel
//     dst write leaving garbage bf16 bits -> NaN patterns). Structural changes re-derived
//     and kept; pack reverted to the verified perm-based sequence.
// R6 = R5 structure with verified pack: (a) single 16-row tiles (22 over 8 waves, crit
//     path 3 tiles vs 2 pairs), (b) f32 bias stream (no bf16->f32 shifts), (c) den via
//     ones-MFMA (kills adds/step + entire shuffle-reduce epilogue; den row-aligned with O).

#define M_TOT 87808   // 256*343
#define NTOK  343
#define DIMC  384
#define NHEAD 12
#define QKVN  1152
#define BWIN  256
#define TSLAB (22 * 11 * 512)   // transposed bias slab per head (f32 elements), 495.6KB/head

typedef __bf16 bf16x8 __attribute__((ext_vector_type(8)));
typedef __bf16 bf16x4 __attribute__((ext_vector_type(4)));
typedef float f32x4 __attribute__((ext_vector_type(4)));

__device__ __forceinline__ unsigned short bf16rne(float f) {
  unsigned int u = __float_as_uint(f);
  u += 0x7fffu + ((u >> 16) & 1u);
  return (unsigned short)(u >> 16);
}

__device__ __forceinline__ unsigned int packbf(float lo, float hi) {
  return (unsigned int)bf16rne(lo) | ((unsigned int)bf16rne(hi) << 16);
}

// round-half-up bf16 pack of 4 floats -> fragment for 16x16x16 bf16 MFMA (verified R0-R4)
__device__ __forceinline__ bf16x4 pack_bf16x4(float a, float b, float c, float d) {
  unsigned ua = __float_as_uint(a) + 0x8000u;
  unsigned ub = __float_as_uint(b) + 0x8000u;
  unsigned uc = __float_as_uint(c) + 0x8000u;
  unsigned ud = __float_as_uint(d) + 0x8000u;
  unsigned lo = __builtin_amdgcn_perm(ub, ua, 0x07060302u);
  unsigned hi = __builtin_amdgcn_perm(ud, uc, 0x07060302u);
  union { unsigned u[2]; bf16x4 v; } x;
  x.u[0] = lo; x.u[1] = hi;
  return x.v;
}

// ---------------- prep kernels ----------------

__global__ void cvt_x_kernel(const float* __restrict__ x, unsigned short* __restrict__ xb, int n8) {
  int i = blockIdx.x * 256 + threadIdx.x;
  if (i >= n8) return;
  const float4* xv = (const float4*)x + (size_t)i * 2;
  float4 a = xv[0], b = xv[1];
  uint4 o;
  o.x = packbf(a.x, a.y); o.y = packbf(a.z, a.w);
  o.z = packbf(b.x, b.y); o.w = packbf(b.z, b.w);
  ((uint4*)xb)[i] = o;
}

__global__ void prep_w_kernel(const float* __restrict__ qkv_w, const float* __restrict__ proj_w,
                              unsigned short* __restrict__ wqkvT, unsigned short* __restrict__ wprojT) {
  int tid = blockIdx.x * 256 + threadIdx.x;
  if (tid < QKVN * DIMC) {
    int n = tid / DIMC, k = tid - n * DIMC;
    wqkvT[tid] = bf16rne(qkv_w[(size_t)k * QKVN + n]);
  }
  if (tid < DIMC * DIMC) {
    int n = tid / DIMC, k = tid - n * DIMC;
    wprojT[tid] = bf16rne(proj_w[(size_t)k * DIMC + n]);
  }
}

// Transposed, jt-PAIRED bias (f32, pre * log2e, pad -> -1e30):
// biasT[h][it][jp][q][l15][e], e in 0..7: jt = 2*jp + (e>>2), r = e&3,
// value = bias_table[rel_idx[min(it*16+l15,342)][jt*16+4q+r]][h] * log2e.
// One wave-load (two f32x4/lane) = contiguous 2KB = bias for 2 jt of one 16-row tile.
__global__ void prep_biasT_kernel(const float* __restrict__ bias_table, const int* __restrict__ rel_idx,
                                  float* __restrict__ biasT) {
  int tid = blockIdx.x * 256 + threadIdx.x;
  if (tid >= NHEAD * 22 * 11 * 64) return;
  int l15 = tid & 15;
  int q   = (tid >> 4) & 3;
  int rest = tid >> 6;            // (h*22 + it)*11 + jp
  int jp  = rest % 11;
  int it  = (rest / 11) % 22;
  int h   = rest / (11 * 22);
  int i = it * 16 + l15; if (i > NTOK - 1) i = NTOK - 1;
  const float LOG2E = 1.44269504088896340f;
  float o[8];
  #pragma unroll
  for (int e = 0; e < 8; e++) {
    int jt = 2 * jp + (e >> 2), r = e & 3;
    int j = jt * 16 + 4 * q + r;
    if (j < NTOK) {
      int idx = rel_idx[i * NTOK + j];
      o[e] = bias_table[idx * NHEAD + h] * LOG2E;
    } else {
      o[e] = -1e30f;
    }
  }
  float4* dst = (float4*)(biasT + (size_t)tid * 8);
  dst[0] = make_float4(o[0], o[1], o[2], o[3]);
  dst[1] = make_float4(o[4], o[5], o[6], o[7]);
}

// ---------------- GEMM (A[M][K] bf16, Bt[N][K] bf16, +bias) ----------------
// OUT_MODE 0: f32 row-major [M][Nn].  OUT_MODE 1: bf16 head-major q/k/v[h][m][32].

typedef const __attribute__((address_space(1))) unsigned int* gas_t;
typedef __attribute__((address_space(3))) unsigned int* las_t;

__device__ __forceinline__ void load16_lds(const void* g, void* l) {
  __builtin_amdgcn_global_load_lds((gas_t)g, (las_t)l, 16, 0, 0);
}

template<int OUT_MODE>
__global__ __launch_bounds__(256, 3) void gemm_bt_kernel(
    const unsigned short* __restrict__ A, const unsigned short* __restrict__ Bt,
    const float* __restrict__ bias, void* __restrict__ outp,
    int M, int Nn, int K)
{
  __shared__ __attribute__((aligned(16))) unsigned short Atile[128 * 64];
  __shared__ __attribute__((aligned(16))) unsigned short Btile[128 * 64];
  const int t = threadIdx.x;
  const int lane = t & 63, w = t >> 6;
  const int q = lane >> 4, l15 = lane & 15;
  const int m0 = blockIdx.y * 128, n0 = blockIdx.x * 128;
  const int wm = w >> 1, wn = w & 1;

  f32x4 acc[4][4] = {};

  for (int kk = 0; kk < K; kk += 64) {
    #pragma unroll
    for (int i = 0; i < 4; i++) {
      int chunk = i * 256 + t;
      int r = chunk >> 3, cl = chunk & 7;
      int cg = cl ^ (r & 7);
      load16_lds(A + (size_t)(m0 + r) * K + kk + cg * 8, Atile + chunk * 8);
      load16_lds(Bt + (size_t)(n0 + r) * K + kk + cg * 8, Btile + chunk * 8);
    }
    __syncthreads();
    const bf16x8* As = (const bf16x8*)Atile;
    const bf16x8* Bs = (const bf16x8*)Btile;
    #pragma unroll
    for (int kq = 0; kq < 2; kq++) {
      bf16x8 af[4], bfr[4];
      #pragma unroll
      for (int mt = 0; mt < 4; mt++) {
        int m = wm * 64 + mt * 16 + l15;
        af[mt] = As[m * 8 + ((kq * 4 + q) ^ (m & 7))];
      }
      #pragma unroll
      for (int nt = 0; nt < 4; nt++) {
        int nr = wn * 64 + nt * 16 + l15;
        bfr[nt] = Bs[nr * 8 + ((kq * 4 + q) ^ (nr & 7))];
      }
      #pragma unroll
      for (int mt = 0; mt < 4; mt++)
        #pragma unroll
        for (int nt = 0; nt < 4; nt++)
          acc[mt][nt] = __builtin_amdgcn_mfma_f32_16x16x32_bf16(af[mt], bfr[nt], acc[mt][nt], 0, 0, 0);
    }
    __syncthreads();
  }

  #pragma unroll
  for (int nt = 0; nt < 4; nt++) {
    int nn = n0 + wn * 64 + nt * 16;      // multiple of 16
    float bv = bias[nn + l15];
    #pragma unroll
    for (int mt = 0; mt < 4; mt++) {
      int mb = m0 + wm * 64 + mt * 16 + q * 4;
      #pragma unroll
      for (int r = 0; r < 4; r++) {
        float v = acc[mt][nt][r] + bv;
        if (OUT_MODE == 0) {
          ((float*)outp)[(size_t)(mb + r) * Nn + nn + l15] = v;
        } else {
          int which = nn / DIMC;
          int hh = (nn - which * DIMC) >> 5;
          int d0 = nn & 16;
          size_t off = ((size_t)(which * NHEAD + hh) * M_TOT + (mb + r)) * 32 + d0 + l15;
          ((unsigned short*)outp)[off] = bf16rne(v);
        }
      }
    }
  }
}

// ---------------- attention: one block (512 threads) per (b,h) ----------------

#define VST 360  // V^T LDS row stride (elements)

__global__ __launch_bounds__(512, 4) void attn_kernel(
    const unsigned short* __restrict__ qhead,  // [3][12][M_TOT][32] bf16
    const float* __restrict__ biasT,           // [12][22][11][4][16][8] f32 (pre * log2e)
    unsigned short* __restrict__ attnout)      // [M_TOT][384] bf16
{
  __shared__ __attribute__((aligned(16))) unsigned short Klds[22 * 512]; // fragment-packed
  __shared__ __attribute__((aligned(16))) unsigned short Vt[32 * VST];   // V^T[d][j]
  const int bx = blockIdx.x;
  // XCD head-clustering: blockIdx round-robins over 8 XCDs (bx&7 ~ XCD); give each XCD
  // whole heads so its L2 holds 1-2 bias slabs instead of all 12.
  const int g = bx & 7, s = bx >> 3;            // s in 0..383
  int h, b;
  if (s < 256) { h = g; b = s; }
  else { int j = g * 128 + (s - 256); h = 8 + (j >> 8); b = j & 255; }

  const int t = threadIdx.x;
  const int lane = t & 63, w = t >> 6;     // w in 0..7
  const int q = lane >> 4, l15 = lane & 15;

  const unsigned short* Qslab = qhead + ((size_t)(0 * NHEAD + h) * M_TOT + (size_t)b * NTOK) * 32;
  const unsigned short* Kslab = qhead + ((size_t)(1 * NHEAD + h) * M_TOT + (size_t)b * NTOK) * 32;
  const unsigned short* Vslab = qhead + ((size_t)(2 * NHEAD + h) * M_TOT + (size_t)b * NTOK) * 32;

  // stage K fragment-packed: Klds[jt*512 + lane*8] = K[jt*16 + l15][q*8..]
  for (int jt = w; jt < 22; jt += 8)
    load16_lds(Kslab + (size_t)(jt * 16 + l15) * 32 + q * 8, Klds + jt * 512 + lane * 8);
  // jt=21 rows 343..351 read past the slab into adjacent slab data: finite bf16, masked by bias pad.

  // stage V^T with conflict-free writes
  for (int j = t; j < NTOK; j += 512) {
    #pragma unroll
    for (int c = 0; c < 4; c++) {
      uint4 vd = *(const uint4*)(Vslab + (size_t)j * 32 + c * 8);
      const unsigned short* vs = (const unsigned short*)&vd;
      #pragma unroll
      for (int u = 0; u < 8; u++)
        Vt[(c * 8 + u) * VST + j] = vs[u];
    }
  }
  // zero V^T pad columns j in [343,359) so p=0 * garbage can't make NaN
  for (int idx = t; idx < 32 * 16; idx += 512)
    Vt[(idx >> 4) * VST + NTOK + (idx & 15)] = 0;
  __syncthreads();

  const float CS = 0.17677669529663689f * 1.44269504088896340f;  // scale * log2e

  // ones fragment for the den-MFMA (B-operand all 1.0bf16)
  union { unsigned u[2]; bf16x4 v; } ones_u;
  ones_u.u[0] = 0x3F803F80u; ones_u.u[1] = 0x3F803F80u;
  const bf16x4 ones4 = ones_u.v;

  // each wave: one 16-row tile per iteration; 22 tiles over 8 waves (crit path 3 tiles)
  for (int it = w; it < 22; it += 8) {
    int i0 = it * 16;
    int iq = i0 + l15; iq = iq > (NTOK - 1) ? (NTOK - 1) : iq;
    bf16x8 bq = *(const bf16x8*)(Qslab + (size_t)iq * 32 + q * 8);

    // bias stream base for this tile; one 2KB chunk (2 x f32x4 per lane) per jt-pair
    const float* bpt = biasT + ((size_t)(h * 22 + it) * 11) * 512 + q * 128 + l15 * 8;

    f32x4 o0 = {0.f,0.f,0.f,0.f}, o1 = {0.f,0.f,0.f,0.f};
    f32x4 den = {0.f,0.f,0.f,0.f};

    // one jt step (QK -> bias+exp2 -> pack -> den/PV MFMA), bias already in registers
    auto jt_step = [&](int jt, f32x4 cb) {
      bf16x8 ak = *(const bf16x8*)(Klds + jt * 512 + lane * 8);  // ds_read_b128, stride-1
      f32x4 z = {0.f,0.f,0.f,0.f};
      f32x4 sS = __builtin_amdgcn_mfma_f32_16x16x32_bf16(ak, bq, z, 0, 0, 0);
      float p0 = __builtin_amdgcn_exp2f(fmaf(sS[0], CS, cb[0]));
      float p1 = __builtin_amdgcn_exp2f(fmaf(sS[1], CS, cb[1]));
      float p2 = __builtin_amdgcn_exp2f(fmaf(sS[2], CS, cb[2]));
      float p3 = __builtin_amdgcn_exp2f(fmaf(sS[3], CS, cb[3]));
      bf16x4 pf = pack_bf16x4(p0, p1, p2, p3);
      bf16x4 vf0 = *(const bf16x4*)(Vt + l15 * VST + jt * 16 + 4 * q);
      bf16x4 vf1 = *(const bf16x4*)(Vt + (16 + l15) * VST + jt * 16 + 4 * q);
      den = __builtin_amdgcn_mfma_f32_16x16x16bf16_1k(pf, ones4, den, 0, 0, 0);
      o0  = __builtin_amdgcn_mfma_f32_16x16x16bf16_1k(pf, vf0, o0, 0, 0, 0);
      o1  = __builtin_amdgcn_mfma_f32_16x16x16bf16_1k(pf, vf1, o1, 0, 0, 0);
    };

    // explicit named double-buffer over 11 jt-pair chunks (NO dynamic register indexing):
    // consume chunk c, then issue load of chunk c+2 -> ~2 jt of compute covers L2 latency.
    f32x4 bX0 = *(const f32x4*)(bpt);
    f32x4 bX1 = *(const f32x4*)(bpt + 4);
    f32x4 bY0 = *(const f32x4*)(bpt + 512);
    f32x4 bY1 = *(const f32x4*)(bpt + 516);

    for (int jp = 0; jp < 10; jp += 2) {
      jt_step(2 * jp,     bX0);
      jt_step(2 * jp + 1, bX1);
      bX0 = *(const f32x4*)(bpt + (jp + 2) * 512);       // jp+2 <= 10 always
      bX1 = *(const f32x4*)(bpt + (jp + 2) * 512 + 4);
      jt_step(2 * jp + 2, bY0);
      jt_step(2 * jp + 3, bY1);
      int c3 = (jp + 3 > 10) ? 10 : (jp + 3);            // clamped dead load at jp=8
      bY0 = *(const f32x4*)(bpt + c3 * 512);
      bY1 = *(const f32x4*)(bpt + c3 * 512 + 4);
    }
    jt_step(20, bX0);
    jt_step(21, bX1);

    // den[r] is already row-aligned with o0[r]/o1[r]: row = i0 + 4q + r
    #pragma unroll
    for (int r = 0; r < 4; r++) {
      int row = i0 + 4 * q + r;
      if (row < NTOK) {
        float inv = __builtin_amdgcn_rcpf(den[r]);
        size_t orow = ((size_t)b * NTOK + row) * DIMC + h * 32;
        attnout[orow + l15]      = bf16rne(o0[r] * inv);
        attnout[orow + 16 + l15] = bf16rne(o1[r] * inv);
      }
    }
  }
}

// ---------------- launch ----------------

extern "C" void kernel_launch(void* const* d_in, const int* in_sizes, int n_in,
                              void* d_out, int out_size, void* d_ws, size_t ws_size,
                              hipStream_t stream) {
  const float* x          = (const float*)d_in[0];
  const float* qkv_w      = (const float*)d_in[1];
  const float* qkv_b      = (const float*)d_in[2];
  const float* proj_w     = (const float*)d_in[3];
  const float* proj_b     = (const float*)d_in[4];
  const float* bias_table = (const float*)d_in[5];
  const int*   rel_idx    = (const int*)d_in[6];

  char* p = (char*)d_ws;
  unsigned short* xb      = (unsigned short*)p; p += (size_t)M_TOT * DIMC * 2;      // 67.4 MB
  unsigned short* wqkvT   = (unsigned short*)p; p += (size_t)QKVN * DIMC * 2;       // 0.9 MB
  unsigned short* wprojT  = (unsigned short*)p; p += (size_t)DIMC * DIMC * 2;       // 0.3 MB
  float*          biasT   = (float*)p;          p += (size_t)NHEAD * TSLAB * 4;     // 5.9 MB
  unsigned short* qhead   = (unsigned short*)p; p += (size_t)3 * NHEAD * M_TOT * 32 * 2; // 202.3 MB
  unsigned short* attnout = (unsigned short*)p; p += (size_t)M_TOT * DIMC * 2;      // 67.4 MB

  cvt_x_kernel<<<(M_TOT * DIMC / 8 + 255) / 256, 256, 0, stream>>>(x, xb, M_TOT * DIMC / 8);
  prep_w_kernel<<<(QKVN * DIMC + 255) / 256, 256, 0, stream>>>(qkv_w, proj_w, wqkvT, wprojT);
  prep_biasT_kernel<<<(NHEAD * 22 * 11 * 64 + 255) / 256, 256, 0, stream>>>(bias_table, rel_idx, biasT);
  gemm_bt_kernel<1><<<dim3(QKVN / 128, M_TOT / 128), 256, 0, stream>>>(
      xb, wqkvT, qkv_b, (void*)qhead, M_TOT, QKVN, DIMC);
  attn_kernel<<<BWIN * NHEAD, 512, 0, stream>>>(qhead, biasT, attnout);
  gemm_bt_kernel<0><<<dim3(DIMC / 128, M_TOT / 128), 256, 0, stream>>>(
      attnout, wprojT, proj_b, d_out, M_TOT, DIMC, DIMC);
}

// Round 7
// 564.199 us; speedup vs baseline: 1.5520x; 1.5520x over previous
//
#include <hip/hip_runtime.h>

// WindowAttention3D: x(256,343,384) -> qkv -> per-(b,h) softmax attention (+rel bias) -> proj
// bf16 MFMA, fp32 accum. QKV GEMM writes head-major q/k/v[h][b*343+i][32] so attention
// reads are contiguous; K staged fragment-packed in LDS via global_load_lds; S^T = K*Q^T
// so P exits QK in the A-fragment layout of mfma_16x16x16 for PV (no transpose).
// R1: K must stay in LDS (global K -> vmcnt on QK chain regression).
// R2: duration invariant to wave count -> bias path was the limiter, not occupancy.
// R3: rolling-buffer dynamic index -> scratch spill (rule #20).
// R4: named double-buffer pipelined bf16 bias stream: 213 -> 168us, clean counters. BASE.
// R5/R6: single-tile restructure -> compiler fully unrolled the small jp loop, hoisted all
//     22 bias loads, spilled ~350B/thread to stay at 64 VGPR (FETCH 878MB, WRITE 618MB).
//     (R5's NaN: v_cvt_pk_bf16_f32 asm partial-dst-write suspicion.) REVERTED to R4 shape.
// R7 = R4 + ones-MFMA den ONLY (math HW-verified in R6): den accumulated as f32x4 via
//     mfma(pf, ones) -> row-aligned with O accumulators, kills 6 adds/step + the entire
//     shuffle-reduce epilogue. #pragma unroll 1 on jp loop guards against unroll-hoist.

#define M_TOT 87808   // 256*343
#define NTOK  343
#define DIMC  384
#define NHEAD 12
#define QKVN  1152
#define BWIN  256
#define TSLAB (22 * 11 * 512)   // transposed bias slab per head (bf16 elements)

typedef __bf16 bf16x8 __attribute__((ext_vector_type(8)));
typedef __bf16 bf16x4 __attribute__((ext_vector_type(4)));
typedef float f32x4 __attribute__((ext_vector_type(4)));
typedef unsigned short u16x4 __attribute__((ext_vector_type(4)));
typedef unsigned short u16x8 __attribute__((ext_vector_type(8)));

__device__ __forceinline__ unsigned short bf16rne(float f) {
  unsigned int u = __float_as_uint(f);
  u += 0x7fffu + ((u >> 16) & 1u);
  return (unsigned short)(u >> 16);
}

__device__ __forceinline__ unsigned int packbf(float lo, float hi) {
  return (unsigned int)bf16rne(lo) | ((unsigned int)bf16rne(hi) << 16);
}

// round-half-up bf16 pack of 4 floats -> fragment for 16x16x16 bf16 MFMA (verified R0-R4)
__device__ __forceinline__ bf16x4 pack_bf16x4(float a, float b, float c, float d) {
  unsigned ua = __float_as_uint(a) + 0x8000u;
  unsigned ub = __float_as_uint(b) + 0x8000u;
  unsigned uc = __float_as_uint(c) + 0x8000u;
  unsigned ud = __float_as_uint(d) + 0x8000u;
  unsigned lo = __builtin_amdgcn_perm(ub, ua, 0x07060302u);
  unsigned hi = __builtin_amdgcn_perm(ud, uc, 0x07060302u);
  union { unsigned u[2]; bf16x4 v; } x;
  x.u[0] = lo; x.u[1] = hi;
  return x.v;
}

__device__ __forceinline__ float bf16tof(unsigned short s) {
  return __uint_as_float(((unsigned int)s) << 16);
}

__device__ __forceinline__ u16x4 lo4(u16x8 v) { return __builtin_shufflevector(v, v, 0, 1, 2, 3); }
__device__ __forceinline__ u16x4 hi4(u16x8 v) { return __builtin_shufflevector(v, v, 4, 5, 6, 7); }

// ---------------- prep kernels ----------------

__global__ void cvt_x_kernel(const float* __restrict__ x, unsigned short* __restrict__ xb, int n8) {
  int i = blockIdx.x * 256 + threadIdx.x;
  if (i >= n8) return;
  const float4* xv = (const float4*)x + (size_t)i * 2;
  float4 a = xv[0], b = xv[1];
  uint4 o;
  o.x = packbf(a.x, a.y); o.y = packbf(a.z, a.w);
  o.z = packbf(b.x, b.y); o.w = packbf(b.z, b.w);
  ((uint4*)xb)[i] = o;
}

__global__ void prep_w_kernel(const float* __restrict__ qkv_w, const float* __restrict__ proj_w,
                              unsigned short* __restrict__ wqkvT, unsigned short* __restrict__ wprojT) {
  int tid = blockIdx.x * 256 + threadIdx.x;
  if (tid < QKVN * DIMC) {
    int n = tid / DIMC, k = tid - n * DIMC;
    wqkvT[tid] = bf16rne(qkv_w[(size_t)k * QKVN + n]);
  }
  if (tid < DIMC * DIMC) {
    int n = tid / DIMC, k = tid - n * DIMC;
    wprojT[tid] = bf16rne(proj_w[(size_t)k * DIMC + n]);
  }
}

// Transposed, jt-PAIRED bias (bf16, pre * log2e, pad -> -1e30):
// biasT[h][it][jp][q][l15][e], e in 0..7: jt = 2*jp + (e>>2), r = e&3,
// value = bias_table[rel_idx[min(it*16+l15,342)][jt*16+4q+r]][h] * log2e.
// One wave-load (u16x8/lane) = contiguous 1KB = bias for 2 jt of one 16-row tile.
__global__ void prep_biasT_kernel(const float* __restrict__ bias_table, const int* __restrict__ rel_idx,
                                  unsigned short* __restrict__ biasT) {
  int tid = blockIdx.x * 256 + threadIdx.x;
  if (tid >= NHEAD * 22 * 11 * 64) return;
  int l15 = tid & 15;
  int q   = (tid >> 4) & 3;
  int rest = tid >> 6;            // (h*22 + it)*11 + jp
  int jp  = rest % 11;
  int it  = (rest / 11) % 22;
  int h   = rest / (11 * 22);
  int i = it * 16 + l15; if (i > NTOK - 1) i = NTOK - 1;
  const float LOG2E = 1.44269504088896340f;
  u16x8 out;
  #pragma unroll
  for (int e = 0; e < 8; e++) {
    int jt = 2 * jp + (e >> 2), r = e & 3;
    int j = jt * 16 + 4 * q + r;
    float v;
    if (j < NTOK) {
      int idx = rel_idx[i * NTOK + j];
      v = bias_table[idx * NHEAD + h] * LOG2E;
    } else {
      v = -1e30f;
    }
    out[e] = bf16rne(v);
  }
  *(u16x8*)(biasT + (size_t)tid * 8) = out;
}

// ---------------- GEMM (A[M][K] bf16, Bt[N][K] bf16, +bias) ----------------
// OUT_MODE 0: f32 row-major [M][Nn].  OUT_MODE 1: bf16 head-major q/k/v[h][m][32].

typedef const __attribute__((address_space(1))) unsigned int* gas_t;
typedef __attribute__((address_space(3))) unsigned int* las_t;

__device__ __forceinline__ void load16_lds(const void* g, void* l) {
  __builtin_amdgcn_global_load_lds((gas_t)g, (las_t)l, 16, 0, 0);
}

template<int OUT_MODE>
__global__ __launch_bounds__(256, 3) void gemm_bt_kernel(
    const unsigned short* __restrict__ A, const unsigned short* __restrict__ Bt,
    const float* __restrict__ bias, void* __restrict__ outp,
    int M, int Nn, int K)
{
  __shared__ __attribute__((aligned(16))) unsigned short Atile[128 * 64];
  __shared__ __attribute__((aligned(16))) unsigned short Btile[128 * 64];
  const int t = threadIdx.x;
  const int lane = t & 63, w = t >> 6;
  const int q = lane >> 4, l15 = lane & 15;
  const int m0 = blockIdx.y * 128, n0 = blockIdx.x * 128;
  const int wm = w >> 1, wn = w & 1;

  f32x4 acc[4][4] = {};

  for (int kk = 0; kk < K; kk += 64) {
    #pragma unroll
    for (int i = 0; i < 4; i++) {
      int chunk = i * 256 + t;
      int r = chunk >> 3, cl = chunk & 7;
      int cg = cl ^ (r & 7);
      load16_lds(A + (size_t)(m0 + r) * K + kk + cg * 8, Atile + chunk * 8);
      load16_lds(Bt + (size_t)(n0 + r) * K + kk + cg * 8, Btile + chunk * 8);
    }
    __syncthreads();
    const bf16x8* As = (const bf16x8*)Atile;
    const bf16x8* Bs = (const bf16x8*)Btile;
    #pragma unroll
    for (int kq = 0; kq < 2; kq++) {
      bf16x8 af[4], bfr[4];
      #pragma unroll
      for (int mt = 0; mt < 4; mt++) {
        int m = wm * 64 + mt * 16 + l15;
        af[mt] = As[m * 8 + ((kq * 4 + q) ^ (m & 7))];
      }
      #pragma unroll
      for (int nt = 0; nt < 4; nt++) {
        int nr = wn * 64 + nt * 16 + l15;
        bfr[nt] = Bs[nr * 8 + ((kq * 4 + q) ^ (nr & 7))];
      }
      #pragma unroll
      for (int mt = 0; mt < 4; mt++)
        #pragma unroll
        for (int nt = 0; nt < 4; nt++)
          acc[mt][nt] = __builtin_amdgcn_mfma_f32_16x16x32_bf16(af[mt], bfr[nt], acc[mt][nt], 0, 0, 0);
    }
    __syncthreads();
  }

  #pragma unroll
  for (int nt = 0; nt < 4; nt++) {
    int nn = n0 + wn * 64 + nt * 16;      // multiple of 16
    float bv = bias[nn + l15];
    #pragma unroll
    for (int mt = 0; mt < 4; mt++) {
      int mb = m0 + wm * 64 + mt * 16 + q * 4;
      #pragma unroll
      for (int r = 0; r < 4; r++) {
        float v = acc[mt][nt][r] + bv;
        if (OUT_MODE == 0) {
          ((float*)outp)[(size_t)(mb + r) * Nn + nn + l15] = v;
        } else {
          int which = nn / DIMC;
          int hh = (nn - which * DIMC) >> 5;
          int d0 = nn & 16;
          size_t off = ((size_t)(which * NHEAD + hh) * M_TOT + (mb + r)) * 32 + d0 + l15;
          ((unsigned short*)outp)[off] = bf16rne(v);
        }
      }
    }
  }
}

// ---------------- attention: one block (512 threads) per (b,h) ----------------

#define VST 360  // V^T LDS row stride (elements)

__global__ __launch_bounds__(512, 4) void attn_kernel(
    const unsigned short* __restrict__ qhead,  // [3][12][M_TOT][32] bf16
    const unsigned short* __restrict__ biasT,  // [12][22][11][4][16][8] bf16 (pre * log2e)
    unsigned short* __restrict__ attnout)      // [M_TOT][384] bf16
{
  __shared__ __attribute__((aligned(16))) unsigned short Klds[22 * 512]; // fragment-packed
  __shared__ __attribute__((aligned(16))) unsigned short Vt[32 * VST];   // V^T[d][j]
  const int bx = blockIdx.x;
  // XCD head-clustering: blockIdx round-robins over 8 XCDs (bx&7 ~ XCD); give each XCD
  // whole heads so its L2 holds 1-2 bias slabs instead of all 12.
  const int g = bx & 7, s = bx >> 3;            // s in 0..383
  int h, b;
  if (s < 256) { h = g; b = s; }
  else { int j = g * 128 + (s - 256); h = 8 + (j >> 8); b = j & 255; }

  const int t = threadIdx.x;
  const int lane = t & 63, w = t >> 6;     // w in 0..7
  const int q = lane >> 4, l15 = lane & 15;

  const unsigned short* Qslab = qhead + ((size_t)(0 * NHEAD + h) * M_TOT + (size_t)b * NTOK) * 32;
  const unsigned short* Kslab = qhead + ((size_t)(1 * NHEAD + h) * M_TOT + (size_t)b * NTOK) * 32;
  const unsigned short* Vslab = qhead + ((size_t)(2 * NHEAD + h) * M_TOT + (size_t)b * NTOK) * 32;

  // stage K fragment-packed: Klds[jt*512 + lane*8] = K[jt*16 + l15][q*8..]
  for (int jt = w; jt < 22; jt += 8)
    load16_lds(Kslab + (size_t)(jt * 16 + l15) * 32 + q * 8, Klds + jt * 512 + lane * 8);
  // jt=21 rows 343..351 read past the slab into adjacent slab data: finite bf16, masked by bias pad.

  // stage V^T with conflict-free writes
  for (int j = t; j < NTOK; j += 512) {
    #pragma unroll
    for (int c = 0; c < 4; c++) {
      uint4 vd = *(const uint4*)(Vslab + (size_t)j * 32 + c * 8);
      const unsigned short* vs = (const unsigned short*)&vd;
      #pragma unroll
      for (int u = 0; u < 8; u++)
        Vt[(c * 8 + u) * VST + j] = vs[u];
    }
  }
  // zero V^T pad columns j in [343,359) so p=0 * garbage can't make NaN
  for (int idx = t; idx < 32 * 16; idx += 512)
    Vt[(idx >> 4) * VST + NTOK + (idx & 15)] = 0;
  __syncthreads();

  const float CS = 0.17677669529663689f * 1.44269504088896340f;  // scale * log2e

  // ones fragment for the den-MFMA (B-operand all 1.0bf16): D[i][j] = sum_k P[i][k]
  union { unsigned u[2]; bf16x4 v; } ones_u;
  ones_u.u[0] = 0x3F803F80u; ones_u.u[1] = 0x3F803F80u;
  const bf16x4 ones4 = ones_u.v;

  // each wave: 32 query rows (two 16-row tiles A,B) per iteration; 11 pairs over 8 waves
  for (int pr = w; pr < 11; pr += 8) {
    int i0 = pr * 32;
    int iqA = i0 + l15;      iqA = iqA > (NTOK - 1) ? (NTOK - 1) : iqA;
    int iqB = i0 + 16 + l15; iqB = iqB > (NTOK - 1) ? (NTOK - 1) : iqB;
    bf16x8 bqA = *(const bf16x8*)(Qslab + (size_t)iqA * 32 + q * 8);
    bf16x8 bqB = *(const bf16x8*)(Qslab + (size_t)iqB * 32 + q * 8);

    // bias stream bases for row tiles it=2pr (A) / 2pr+1 (B); one u16x8 per jt-pair chunk
    const unsigned short* bApt = biasT + ((size_t)(h * 22 + pr * 2) * 11) * 512 + q * 128 + l15 * 8;
    const unsigned short* bBpt = bApt + 11 * 512;

    f32x4 oA0 = {0.f,0.f,0.f,0.f}, oA1 = {0.f,0.f,0.f,0.f};
    f32x4 oB0 = {0.f,0.f,0.f,0.f}, oB1 = {0.f,0.f,0.f,0.f};
    f32x4 denA4 = {0.f,0.f,0.f,0.f}, denB4 = {0.f,0.f,0.f,0.f};

    // one jt step (QK -> bias+exp2 -> PV + den-MFMA) with bias fragments in registers
    auto jt_step = [&](int jt, u16x4 cbA, u16x4 cbB) {
      bf16x8 ak = *(const bf16x8*)(Klds + jt * 512 + lane * 8);  // ds_read_b128, stride-1
      f32x4 z = {0.f,0.f,0.f,0.f};
      f32x4 sA = __builtin_amdgcn_mfma_f32_16x16x32_bf16(ak, bqA, z, 0, 0, 0);
      f32x4 sB = __builtin_amdgcn_mfma_f32_16x16x32_bf16(ak, bqB, z, 0, 0, 0);
      float pA0 = __builtin_amdgcn_exp2f(fmaf(sA[0], CS, bf16tof(cbA[0])));
      float pA1 = __builtin_amdgcn_exp2f(fmaf(sA[1], CS, bf16tof(cbA[1])));
      float pA2 = __builtin_amdgcn_exp2f(fmaf(sA[2], CS, bf16tof(cbA[2])));
      float pA3 = __builtin_amdgcn_exp2f(fmaf(sA[3], CS, bf16tof(cbA[3])));
      float pB0 = __builtin_amdgcn_exp2f(fmaf(sB[0], CS, bf16tof(cbB[0])));
      float pB1 = __builtin_amdgcn_exp2f(fmaf(sB[1], CS, bf16tof(cbB[1])));
      float pB2 = __builtin_amdgcn_exp2f(fmaf(sB[2], CS, bf16tof(cbB[2])));
      float pB3 = __builtin_amdgcn_exp2f(fmaf(sB[3], CS, bf16tof(cbB[3])));
      bf16x4 pfA = pack_bf16x4(pA0, pA1, pA2, pA3);
      bf16x4 pfB = pack_bf16x4(pB0, pB1, pB2, pB3);
      bf16x4 vf0 = *(const bf16x4*)(Vt + l15 * VST + jt * 16 + 4 * q);
      bf16x4 vf1 = *(const bf16x4*)(Vt + (16 + l15) * VST + jt * 16 + 4 * q);
      denA4 = __builtin_amdgcn_mfma_f32_16x16x16bf16_1k(pfA, ones4, denA4, 0, 0, 0);
      denB4 = __builtin_amdgcn_mfma_f32_16x16x16bf16_1k(pfB, ones4, denB4, 0, 0, 0);
      oA0 = __builtin_amdgcn_mfma_f32_16x16x16bf16_1k(pfA, vf0, oA0, 0, 0, 0);
      oA1 = __builtin_amdgcn_mfma_f32_16x16x16bf16_1k(pfA, vf1, oA1, 0, 0, 0);
      oB0 = __builtin_amdgcn_mfma_f32_16x16x16bf16_1k(pfB, vf0, oB0, 0, 0, 0);
      oB1 = __builtin_amdgcn_mfma_f32_16x16x16bf16_1k(pfB, vf1, oB1, 0, 0, 0);
    };

    // explicit named double-buffer over 11 jt-pair chunks (NO dynamic register indexing):
    // consume chunk c, then issue load of chunk c+2 -> ~2 jt of compute covers L2 latency.
    // unroll 1: keep the loop rolled so the scheduler can't hoist all chunk loads (R6 spill).
    u16x8 bufX_A = *(const u16x8*)(bApt);
    u16x8 bufX_B = *(const u16x8*)(bBpt);
    u16x8 bufY_A = *(const u16x8*)(bApt + 512);
    u16x8 bufY_B = *(const u16x8*)(bBpt + 512);

    #pragma unroll 1
    for (int jp = 0; jp < 10; jp += 2) {
      jt_step(2 * jp,     lo4(bufX_A), lo4(bufX_B));
      jt_step(2 * jp + 1, hi4(bufX_A), hi4(bufX_B));
      bufX_A = *(const u16x8*)(bApt + (jp + 2) * 512);       // jp+2 <= 10 always
      bufX_B = *(const u16x8*)(bBpt + (jp + 2) * 512);
      jt_step(2 * jp + 2, lo4(bufY_A), lo4(bufY_B));
      jt_step(2 * jp + 3, hi4(bufY_A), hi4(bufY_B));
      int c3 = (jp + 3 > 10) ? 10 : (jp + 3);                // clamped dead load at jp=8
      bufY_A = *(const u16x8*)(bApt + c3 * 512);
      bufY_B = *(const u16x8*)(bBpt + c3 * 512);
    }
    jt_step(20, lo4(bufX_A), lo4(bufX_B));
    jt_step(21, hi4(bufX_A), hi4(bufX_B));

    // denA4[r]/denB4[r] are row-aligned with oA*/oB*: row = i0 + 4q + r (A), +16 (B)
    #pragma unroll
    for (int r = 0; r < 4; r++) {
      int rr = 4 * q + r;
      int iA = i0 + rr, iB = i0 + 16 + rr;
      if (iA < NTOK) {
        float inv = __builtin_amdgcn_rcpf(denA4[r]);
        size_t orow = ((size_t)b * NTOK + iA) * DIMC + h * 32;
        attnout[orow + l15]      = bf16rne(oA0[r] * inv);
        attnout[orow + 16 + l15] = bf16rne(oA1[r] * inv);
      }
      if (iB < NTOK) {
        float inv = __builtin_amdgcn_rcpf(denB4[r]);
        size_t orow = ((size_t)b * NTOK + iB) * DIMC + h * 32;
        attnout[orow + l15]      = bf16rne(oB0[r] * inv);
        attnout[orow + 16 + l15] = bf16rne(oB1[r] * inv);
      }
    }
  }
}

// ---------------- launch ----------------

extern "C" void kernel_launch(void* const* d_in, const int* in_sizes, int n_in,
                              void* d_out, int out_size, void* d_ws, size_t ws_size,
                              hipStream_t stream) {
  const float* x          = (const float*)d_in[0];
  const float* qkv_w      = (const float*)d_in[1];
  const float* qkv_b      = (const float*)d_in[2];
  const float* proj_w     = (const float*)d_in[3];
  const float* proj_b     = (const float*)d_in[4];
  const float* bias_table = (const float*)d_in[5];
  const int*   rel_idx    = (const int*)d_in[6];

  char* p = (char*)d_ws;
  unsigned short* xb      = (unsigned short*)p; p += (size_t)M_TOT * DIMC * 2;      // 67.4 MB
  unsigned short* wqkvT   = (unsigned short*)p; p += (size_t)QKVN * DIMC * 2;       // 0.9 MB
  unsigned short* wprojT  = (unsigned short*)p; p += (size_t)DIMC * DIMC * 2;       // 0.3 MB
  unsigned short* biasT   = (unsigned short*)p; p += (size_t)NHEAD * TSLAB * 2;     // 3.0 MB
  unsigned short* qhead   = (unsigned short*)p; p += (size_t)3 * NHEAD * M_TOT * 32 * 2; // 202.3 MB
  unsigned short* attnout = (unsigned short*)p; p += (size_t)M_TOT * DIMC * 2;      // 67.4 MB

  cvt_x_kernel<<<(M_TOT * DIMC / 8 + 255) / 256, 256, 0, stream>>>(x, xb, M_TOT * DIMC / 8);
  prep_w_kernel<<<(QKVN * DIMC + 255) / 256, 256, 0, stream>>>(qkv_w, proj_w, wqkvT, wprojT);
  prep_biasT_kernel<<<(NHEAD * 22 * 11 * 64 + 255) / 256, 256, 0, stream>>>(bias_table, rel_idx, biasT);
  gemm_bt_kernel<1><<<dim3(QKVN / 128, M_TOT / 128), 256, 0, stream>>>(
      xb, wqkvT, qkv_b, (void*)qhead, M_TOT, QKVN, DIMC);
  attn_kernel<<<BWIN * NHEAD, 512, 0, stream>>>(qhead, biasT, attnout);
  gemm_bt_kernel<0><<<dim3(DIMC / 128, M_TOT / 128), 256, 0, stream>>>(
      attnout, wprojT, proj_b, d_out, M_TOT, DIMC, DIMC);
}

// Round 8
// 557.844 us; speedup vs baseline: 1.5697x; 1.0114x over previous
//
#include <hip/hip_runtime.h>

// WindowAttention3D: x(256,343,384) -> qkv -> per-(b,h) softmax attention (+rel bias) -> proj
// bf16 MFMA, fp32 accum. QKV GEMM writes head-major q/k/v[h][b*343+i][32] so attention
// reads are contiguous; K staged fragment-packed in LDS via global_load_lds; S^T = K*Q^T
// so P exits QK in the A-fragment layout of mfma_16x16x16 for PV (no transpose).
// R1: K must stay in LDS. R2: occupancy not the limiter; bias path was.
// R3: dynamic reg index -> spill (rule #20). R4: named double-buffer bias: 213->168us.
// R5/R6: restructure let the compiler unroll+hoist -> spill storm; REVERTED.
// R7: R4 + ones-MFMA den (row-aligned with O, no shuffle epilogue) + unroll-1 guard:
//     168 -> 154.6us, clean counters (VGPR 56, no spill). BASE.
// R8: per-score VALU cuts, shape unchanged: (a) Q pre-scaled by scale*log2e in GEMM
//     epilogue -> attn bias add is s+b (v_pk_add_f32), f32 bias stream (R6-verified prep);
//     (b) P-pack via compiler bf16 casts (v_cvt_pk_bf16_f32, RNE — no hand asm);
//     (c) VST 360->362 (odd dword stride -> <=2-way V-read bank aliasing).

#define M_TOT 87808   // 256*343
#define NTOK  343
#define DIMC  384
#define NHEAD 12
#define QKVN  1152
#define BWIN  256
#define TSLAB (22 * 11 * 512)   // transposed bias slab per head (f32 elements)

typedef __bf16 bf16x8 __attribute__((ext_vector_type(8)));
typedef __bf16 bf16x4 __attribute__((ext_vector_type(4)));
typedef float f32x4 __attribute__((ext_vector_type(4)));

__device__ __forceinline__ unsigned short bf16rne(float f) {
  unsigned int u = __float_as_uint(f);
  u += 0x7fffu + ((u >> 16) & 1u);
  return (unsigned short)(u >> 16);
}

__device__ __forceinline__ unsigned int packbf(float lo, float hi) {
  return (unsigned int)bf16rne(lo) | ((unsigned int)bf16rne(hi) << 16);
}

// round-half-up bf16 pack of 4 floats (kept for prep kernels)
__device__ __forceinline__ bf16x4 pack_bf16x4(float a, float b, float c, float d) {
  unsigned ua = __float_as_uint(a) + 0x8000u;
  unsigned ub = __float_as_uint(b) + 0x8000u;
  unsigned uc = __float_as_uint(c) + 0x8000u;
  unsigned ud = __float_as_uint(d) + 0x8000u;
  unsigned lo = __builtin_amdgcn_perm(ub, ua, 0x07060302u);
  unsigned hi = __builtin_amdgcn_perm(ud, uc, 0x07060302u);
  union { unsigned u[2]; bf16x4 v; } x;
  x.u[0] = lo; x.u[1] = hi;
  return x.v;
}

// ---------------- prep kernels ----------------

__global__ void cvt_x_kernel(const float* __restrict__ x, unsigned short* __restrict__ xb, int n8) {
  int i = blockIdx.x * 256 + threadIdx.x;
  if (i >= n8) return;
  const float4* xv = (const float4*)x + (size_t)i * 2;
  float4 a = xv[0], b = xv[1];
  uint4 o;
  o.x = packbf(a.x, a.y); o.y = packbf(a.z, a.w);
  o.z = packbf(b.x, b.y); o.w = packbf(b.z, b.w);
  ((uint4*)xb)[i] = o;
}

__global__ void prep_w_kernel(const float* __restrict__ qkv_w, const float* __restrict__ proj_w,
                              unsigned short* __restrict__ wqkvT, unsigned short* __restrict__ wprojT) {
  int tid = blockIdx.x * 256 + threadIdx.x;
  if (tid < QKVN * DIMC) {
    int n = tid / DIMC, k = tid - n * DIMC;
    wqkvT[tid] = bf16rne(qkv_w[(size_t)k * QKVN + n]);
  }
  if (tid < DIMC * DIMC) {
    int n = tid / DIMC, k = tid - n * DIMC;
    wprojT[tid] = bf16rne(proj_w[(size_t)k * DIMC + n]);
  }
}

// Transposed, jt-PAIRED bias (f32, pre * log2e, pad -> -1e30) — R6-verified layout:
// biasT[h][it][jp][q][l15][e], e in 0..7: jt = 2*jp + (e>>2), r = e&3,
// value = bias_table[rel_idx[min(it*16+l15,342)][jt*16+4q+r]][h] * log2e.
__global__ void prep_biasT_kernel(const float* __restrict__ bias_table, const int* __restrict__ rel_idx,
                                  float* __restrict__ biasT) {
  int tid = blockIdx.x * 256 + threadIdx.x;
  if (tid >= NHEAD * 22 * 11 * 64) return;
  int l15 = tid & 15;
  int q   = (tid >> 4) & 3;
  int rest = tid >> 6;            // (h*22 + it)*11 + jp
  int jp  = rest % 11;
  int it  = (rest / 11) % 22;
  int h   = rest / (11 * 22);
  int i = it * 16 + l15; if (i > NTOK - 1) i = NTOK - 1;
  const float LOG2E = 1.44269504088896340f;
  float o[8];
  #pragma unroll
  for (int e = 0; e < 8; e++) {
    int jt = 2 * jp + (e >> 2), r = e & 3;
    int j = jt * 16 + 4 * q + r;
    if (j < NTOK) {
      int idx = rel_idx[i * NTOK + j];
      o[e] = bias_table[idx * NHEAD + h] * LOG2E;
    } else {
      o[e] = -1e30f;
    }
  }
  float4* dst = (float4*)(biasT + (size_t)tid * 8);
  dst[0] = make_float4(o[0], o[1], o[2], o[3]);
  dst[1] = make_float4(o[4], o[5], o[6], o[7]);
}

// ---------------- GEMM (A[M][K] bf16, Bt[N][K] bf16, +bias) ----------------
// OUT_MODE 0: f32 row-major [M][Nn].  OUT_MODE 1: bf16 head-major q/k/v[h][m][32],
//             with the q third (which==0) pre-scaled by scale*log2e for the attn kernel.

typedef const __attribute__((address_space(1))) unsigned int* gas_t;
typedef __attribute__((address_space(3))) unsigned int* las_t;

__device__ __forceinline__ void load16_lds(const void* g, void* l) {
  __builtin_amdgcn_global_load_lds((gas_t)g, (las_t)l, 16, 0, 0);
}

template<int OUT_MODE>
__global__ __launch_bounds__(256, 3) void gemm_bt_kernel(
    const unsigned short* __restrict__ A, const unsigned short* __restrict__ Bt,
    const float* __restrict__ bias, void* __restrict__ outp,
    int M, int Nn, int K)
{
  __shared__ __attribute__((aligned(16))) unsigned short Atile[128 * 64];
  __shared__ __attribute__((aligned(16))) unsigned short Btile[128 * 64];
  const int t = threadIdx.x;
  const int lane = t & 63, w = t >> 6;
  const int q = lane >> 4, l15 = lane & 15;
  const int m0 = blockIdx.y * 128, n0 = blockIdx.x * 128;
  const int wm = w >> 1, wn = w & 1;

  f32x4 acc[4][4] = {};

  for (int kk = 0; kk < K; kk += 64) {
    #pragma unroll
    for (int i = 0; i < 4; i++) {
      int chunk = i * 256 + t;
      int r = chunk >> 3, cl = chunk & 7;
      int cg = cl ^ (r & 7);
      load16_lds(A + (size_t)(m0 + r) * K + kk + cg * 8, Atile + chunk * 8);
      load16_lds(Bt + (size_t)(n0 + r) * K + kk + cg * 8, Btile + chunk * 8);
    }
    __syncthreads();
    const bf16x8* As = (const bf16x8*)Atile;
    const bf16x8* Bs = (const bf16x8*)Btile;
    #pragma unroll
    for (int kq = 0; kq < 2; kq++) {
      bf16x8 af[4], bfr[4];
      #pragma unroll
      for (int mt = 0; mt < 4; mt++) {
        int m = wm * 64 + mt * 16 + l15;
        af[mt] = As[m * 8 + ((kq * 4 + q) ^ (m & 7))];
      }
      #pragma unroll
      for (int nt = 0; nt < 4; nt++) {
        int nr = wn * 64 + nt * 16 + l15;
        bfr[nt] = Bs[nr * 8 + ((kq * 4 + q) ^ (nr & 7))];
      }
      #pragma unroll
      for (int mt = 0; mt < 4; mt++)
        #pragma unroll
        for (int nt = 0; nt < 4; nt++)
          acc[mt][nt] = __builtin_amdgcn_mfma_f32_16x16x32_bf16(af[mt], bfr[nt], acc[mt][nt], 0, 0, 0);
    }
    __syncthreads();
  }

  const float QSC = 0.17677669529663689f * 1.44269504088896340f;  // scale * log2e
  #pragma unroll
  for (int nt = 0; nt < 4; nt++) {
    int nn = n0 + wn * 64 + nt * 16;      // multiple of 16
    float bv = bias[nn + l15];
    #pragma unroll
    for (int mt = 0; mt < 4; mt++) {
      int mb = m0 + wm * 64 + mt * 16 + q * 4;
      #pragma unroll
      for (int r = 0; r < 4; r++) {
        float v = acc[mt][nt][r] + bv;
        if (OUT_MODE == 0) {
          ((float*)outp)[(size_t)(mb + r) * Nn + nn + l15] = v;
        } else {
          int which = nn / DIMC;
          if (which == 0) v *= QSC;   // pre-scale q so attn does s+b (no fma, no CS)
          int hh = (nn - which * DIMC) >> 5;
          int d0 = nn & 16;
          size_t off = ((size_t)(which * NHEAD + hh) * M_TOT + (mb + r)) * 32 + d0 + l15;
          ((unsigned short*)outp)[off] = bf16rne(v);
        }
      }
    }
  }
}

// ---------------- attention: one block (512 threads) per (b,h) ----------------

#define VST 362  // V^T LDS row stride (elements); odd dword stride (181) -> <=2-way bank aliasing

__global__ __launch_bounds__(512, 4) void attn_kernel(
    const unsigned short* __restrict__ qhead,  // [3][12][M_TOT][32] bf16 (q pre-scaled)
    const float* __restrict__ biasT,           // [12][22][11][4][16][8] f32 (pre * log2e)
    unsigned short* __restrict__ attnout)      // [M_TOT][384] bf16
{
  __shared__ __attribute__((aligned(16))) unsigned short Klds[22 * 512]; // fragment-packed
  __shared__ __attribute__((aligned(16))) unsigned short Vt[32 * VST];   // V^T[d][j]
  const int bx = blockIdx.x;
  // XCD head-clustering: blockIdx round-robins over 8 XCDs (bx&7 ~ XCD); give each XCD
  // whole heads so its L2 holds 1-2 bias slabs instead of all 12.
  const int g = bx & 7, s = bx >> 3;            // s in 0..383
  int h, b;
  if (s < 256) { h = g; b = s; }
  else { int j = g * 128 + (s - 256); h = 8 + (j >> 8); b = j & 255; }

  const int t = threadIdx.x;
  const int lane = t & 63, w = t >> 6;     // w in 0..7
  const int q = lane >> 4, l15 = lane & 15;

  const unsigned short* Qslab = qhead + ((size_t)(0 * NHEAD + h) * M_TOT + (size_t)b * NTOK) * 32;
  const unsigned short* Kslab = qhead + ((size_t)(1 * NHEAD + h) * M_TOT + (size_t)b * NTOK) * 32;
  const unsigned short* Vslab = qhead + ((size_t)(2 * NHEAD + h) * M_TOT + (size_t)b * NTOK) * 32;

  // stage K fragment-packed: Klds[jt*512 + lane*8] = K[jt*16 + l15][q*8..]
  for (int jt = w; jt < 22; jt += 8)
    load16_lds(Kslab + (size_t)(jt * 16 + l15) * 32 + q * 8, Klds + jt * 512 + lane * 8);
  // jt=21 rows 343..351 read past the slab into adjacent slab data: finite bf16, masked by bias pad.

  // stage V^T with conflict-free writes
  for (int j = t; j < NTOK; j += 512) {
    #pragma unroll
    for (int c = 0; c < 4; c++) {
      uint4 vd = *(const uint4*)(Vslab + (size_t)j * 32 + c * 8);
      const unsigned short* vs = (const unsigned short*)&vd;
      #pragma unroll
      for (int u = 0; u < 8; u++)
        Vt[(c * 8 + u) * VST + j] = vs[u];
    }
  }
  // zero V^T pad columns j in [343,359) so p=0 * garbage can't make NaN
  for (int idx = t; idx < 32 * 16; idx += 512)
    Vt[(idx >> 4) * VST + NTOK + (idx & 15)] = 0;
  __syncthreads();

  // ones fragment for the den-MFMA (B-operand all 1.0bf16): D[i][j] = sum_k P[i][k]
  union { unsigned u[2]; bf16x4 v; } ones_u;
  ones_u.u[0] = 0x3F803F80u; ones_u.u[1] = 0x3F803F80u;
  const bf16x4 ones4 = ones_u.v;

  // each wave: 32 query rows (two 16-row tiles A,B) per iteration; 11 pairs over 8 waves
  for (int pr = w; pr < 11; pr += 8) {
    int i0 = pr * 32;
    int iqA = i0 + l15;      iqA = iqA > (NTOK - 1) ? (NTOK - 1) : iqA;
    int iqB = i0 + 16 + l15; iqB = iqB > (NTOK - 1) ? (NTOK - 1) : iqB;
    bf16x8 bqA = *(const bf16x8*)(Qslab + (size_t)iqA * 32 + q * 8);
    bf16x8 bqB = *(const bf16x8*)(Qslab + (size_t)iqB * 32 + q * 8);

    // bias stream bases for row tiles it=2pr (A) / 2pr+1 (B); 2KB (2 f32x4/lane) per jt-pair
    const float* bApt = biasT + ((size_t)(h * 22 + pr * 2) * 11) * 512 + q * 128 + l15 * 8;
    const float* bBpt = bApt + 11 * 512;

    f32x4 oA0 = {0.f,0.f,0.f,0.f}, oA1 = {0.f,0.f,0.f,0.f};
    f32x4 oB0 = {0.f,0.f,0.f,0.f}, oB1 = {0.f,0.f,0.f,0.f};
    f32x4 denA4 = {0.f,0.f,0.f,0.f}, denB4 = {0.f,0.f,0.f,0.f};

    // one jt step: QK -> (s+b) -> exp2 -> bf16 cast pack -> den/PV MFMAs
    auto jt_step = [&](int jt, f32x4 cbA, f32x4 cbB) {
      bf16x8 ak = *(const bf16x8*)(Klds + jt * 512 + lane * 8);  // ds_read_b128, stride-1
      f32x4 z = {0.f,0.f,0.f,0.f};
      f32x4 sA = __builtin_amdgcn_mfma_f32_16x16x32_bf16(ak, bqA, z, 0, 0, 0);
      f32x4 sB = __builtin_amdgcn_mfma_f32_16x16x32_bf16(ak, bqB, z, 0, 0, 0);
      f32x4 psA = sA + cbA;   // v_pk_add_f32 pairs (q pre-scaled by scale*log2e)
      f32x4 psB = sB + cbB;
      float pA0 = __builtin_amdgcn_exp2f(psA[0]);
      float pA1 = __builtin_amdgcn_exp2f(psA[1]);
      float pA2 = __builtin_amdgcn_exp2f(psA[2]);
      float pA3 = __builtin_amdgcn_exp2f(psA[3]);
      float pB0 = __builtin_amdgcn_exp2f(psB[0]);
      float pB1 = __builtin_amdgcn_exp2f(psB[1]);
      float pB2 = __builtin_amdgcn_exp2f(psB[2]);
      float pB3 = __builtin_amdgcn_exp2f(psB[3]);
      bf16x4 pfA = { (__bf16)pA0, (__bf16)pA1, (__bf16)pA2, (__bf16)pA3 };  // v_cvt_pk_bf16_f32
      bf16x4 pfB = { (__bf16)pB0, (__bf16)pB1, (__bf16)pB2, (__bf16)pB3 };
      bf16x4 vf0 = *(const bf16x4*)(Vt + l15 * VST + jt * 16 + 4 * q);
      bf16x4 vf1 = *(const bf16x4*)(Vt + (16 + l15) * VST + jt * 16 + 4 * q);
      denA4 = __builtin_amdgcn_mfma_f32_16x16x16bf16_1k(pfA, ones4, denA4, 0, 0, 0);
      denB4 = __builtin_amdgcn_mfma_f32_16x16x16bf16_1k(pfB, ones4, denB4, 0, 0, 0);
      oA0 = __builtin_amdgcn_mfma_f32_16x16x16bf16_1k(pfA, vf0, oA0, 0, 0, 0);
      oA1 = __builtin_amdgcn_mfma_f32_16x16x16bf16_1k(pfA, vf1, oA1, 0, 0, 0);
      oB0 = __builtin_amdgcn_mfma_f32_16x16x16bf16_1k(pfB, vf0, oB0, 0, 0, 0);
      oB1 = __builtin_amdgcn_mfma_f32_16x16x16bf16_1k(pfB, vf1, oB1, 0, 0, 0);
    };

    // explicit named double-buffer over 11 jt-pair chunks (NO dynamic register indexing):
    // consume chunk c, then issue load of chunk c+2 -> ~2 jt of compute covers L2 latency.
    // unroll 1: keep the loop rolled so the scheduler can't hoist all chunk loads (R6 spill).
    f32x4 bXA0 = *(const f32x4*)(bApt);
    f32x4 bXA1 = *(const f32x4*)(bApt + 4);
    f32x4 bXB0 = *(const f32x4*)(bBpt);
    f32x4 bXB1 = *(const f32x4*)(bBpt + 4);
    f32x4 bYA0 = *(const f32x4*)(bApt + 512);
    f32x4 bYA1 = *(const f32x4*)(bApt + 516);
    f32x4 bYB0 = *(const f32x4*)(bBpt + 512);
    f32x4 bYB1 = *(const f32x4*)(bBpt + 516);

    #pragma unroll 1
    for (int jp = 0; jp < 10; jp += 2) {
      jt_step(2 * jp,     bXA0, bXB0);
      jt_step(2 * jp + 1, bXA1, bXB1);
      bXA0 = *(const f32x4*)(bApt + (jp + 2) * 512);       // jp+2 <= 10 always
      bXA1 = *(const f32x4*)(bApt + (jp + 2) * 512 + 4);
      bXB0 = *(const f32x4*)(bBpt + (jp + 2) * 512);
      bXB1 = *(const f32x4*)(bBpt + (jp + 2) * 512 + 4);
      jt_step(2 * jp + 2, bYA0, bYB0);
      jt_step(2 * jp + 3, bYA1, bYB1);
      int c3 = (jp + 3 > 10) ? 10 : (jp + 3);              // clamped dead load at jp=8
      bYA0 = *(const f32x4*)(bApt + c3 * 512);
      bYA1 = *(const f32x4*)(bApt + c3 * 512 + 4);
      bYB0 = *(const f32x4*)(bBpt + c3 * 512);
      bYB1 = *(const f32x4*)(bBpt + c3 * 512 + 4);
    }
    jt_step(20, bXA0, bXB0);
    jt_step(21, bXA1, bXB1);

    // denA4[r]/denB4[r] are row-aligned with oA*/oB*: row = i0 + 4q + r (A), +16 (B)
    #pragma unroll
    for (int r = 0; r < 4; r++) {
      int rr = 4 * q + r;
      int iA = i0 + rr, iB = i0 + 16 + rr;
      if (iA < NTOK) {
        float inv = __builtin_amdgcn_rcpf(denA4[r]);
        size_t orow = ((size_t)b * NTOK + iA) * DIMC + h * 32;
        attnout[orow + l15]      = bf16rne(oA0[r] * inv);
        attnout[orow + 16 + l15] = bf16rne(oA1[r] * inv);
      }
      if (iB < NTOK) {
        float inv = __builtin_amdgcn_rcpf(denB4[r]);
        size_t orow = ((size_t)b * NTOK + iB) * DIMC + h * 32;
        attnout[orow + l15]      = bf16rne(oB0[r] * inv);
        attnout[orow + 16 + l15] = bf16rne(oB1[r] * inv);
      }
    }
  }
}

// ---------------- launch ----------------

extern "C" void kernel_launch(void* const* d_in, const int* in_sizes, int n_in,
                              void* d_out, int out_size, void* d_ws, size_t ws_size,
                              hipStream_t stream) {
  const float* x          = (const float*)d_in[0];
  const float* qkv_w      = (const float*)d_in[1];
  const float* qkv_b      = (const float*)d_in[2];
  const float* proj_w     = (const float*)d_in[3];
  const float* proj_b     = (const float*)d_in[4];
  const float* bias_table = (const float*)d_in[5];
  const int*   rel_idx    = (const int*)d_in[6];

  char* p = (char*)d_ws;
  unsigned short* xb      = (unsigned short*)p; p += (size_t)M_TOT * DIMC * 2;      // 67.4 MB
  unsigned short* wqkvT   = (unsigned short*)p; p += (size_t)QKVN * DIMC * 2;       // 0.9 MB
  unsigned short* wprojT  = (unsigned short*)p; p += (size_t)DIMC * DIMC * 2;       // 0.3 MB
  float*          biasT   = (float*)p;          p += (size_t)NHEAD * TSLAB * 4;     // 5.9 MB
  unsigned short* qhead   = (unsigned short*)p; p += (size_t)3 * NHEAD * M_TOT * 32 * 2; // 202.3 MB
  unsigned short* attnout = (unsigned short*)p; p += (size_t)M_TOT * DIMC * 2;      // 67.4 MB

  cvt_x_kernel<<<(M_TOT * DIMC / 8 + 255) / 256, 256, 0, stream>>>(x, xb, M_TOT * DIMC / 8);
  prep_w_kernel<<<(QKVN * DIMC + 255) / 256, 256, 0, stream>>>(qkv_w, proj_w, wqkvT, wprojT);
  prep_biasT_kernel<<<(NHEAD * 22 * 11 * 64 + 255) / 256, 256, 0, stream>>>(bias_table, rel_idx, biasT);
  gemm_bt_kernel<1><<<dim3(QKVN / 128, M_TOT / 128), 256, 0, stream>>>(
      xb, wqkvT, qkv_b, (void*)qhead, M_TOT, QKVN, DIMC);
  attn_kernel<<<BWIN * NHEAD, 512, 0, stream>>>(qhead, biasT, attnout);
  gemm_bt_kernel<0><<<dim3(DIMC / 128, M_TOT / 128), 256, 0, stream>>>(
      attnout, wprojT, proj_b, d_out, M_TOT, DIMC, DIMC);
}

// Round 9
// 545.731 us; speedup vs baseline: 1.6045x; 1.0222x over previous
//
#include <hip/hip_runtime.h>

// WindowAttention3D: x(256,343,384) -> qkv -> per-(b,h) softmax attention (+rel bias) -> proj
// bf16 MFMA, fp32 accum. QKV GEMM writes head-major q/k/v[h][b*343+i][32] so attention
// reads are contiguous; K staged fragment-packed in LDS via global_load_lds; S^T = K*Q^T
// so P exits QK in the A-fragment layout of mfma_16x16x16 for PV (no transpose).
// R1: K must stay in LDS. R2: occupancy not the limiter; bias path was.
// R3: dynamic reg index -> spill (rule #20). R4: named double-buffer bias: 213->168us.
// R5/R6: restructure let the compiler unroll+hoist -> spill storm; REVERTED.
// R7: ones-MFMA den + unroll-1 guard: 168 -> 154.6us. R8: Q pre-scaled (s+b pk_add),
//     compiler cvt_pk P-pack: 154.6 -> 143.8us, absmax improved. BASE.
// R9: (a) XCD panel-clustering for BOTH GEMMs (all n-blocks of an m-panel on one XCD ->
//     A-panel L2-resident, 9x/3x reuse instead of cross-XCD L3 re-reads ~600MB);
//     (b) s_setprio(1) around attn's PV/den MFMA cluster (barrier-free waves = the
//     regime where setprio measured +4-7%).

#define M_TOT 87808   // 256*343
#define NTOK  343
#define DIMC  384
#define NHEAD 12
#define QKVN  1152
#define BWIN  256
#define TSLAB (22 * 11 * 512)   // transposed bias slab per head (f32 elements)

typedef __bf16 bf16x8 __attribute__((ext_vector_type(8)));
typedef __bf16 bf16x4 __attribute__((ext_vector_type(4)));
typedef float f32x4 __attribute__((ext_vector_type(4)));

__device__ __forceinline__ unsigned short bf16rne(float f) {
  unsigned int u = __float_as_uint(f);
  u += 0x7fffu + ((u >> 16) & 1u);
  return (unsigned short)(u >> 16);
}

__device__ __forceinline__ unsigned int packbf(float lo, float hi) {
  return (unsigned int)bf16rne(lo) | ((unsigned int)bf16rne(hi) << 16);
}

// ---------------- prep kernels ----------------

__global__ void cvt_x_kernel(const float* __restrict__ x, unsigned short* __restrict__ xb, int n8) {
  int i = blockIdx.x * 256 + threadIdx.x;
  if (i >= n8) return;
  const float4* xv = (const float4*)x + (size_t)i * 2;
  float4 a = xv[0], b = xv[1];
  uint4 o;
  o.x = packbf(a.x, a.y); o.y = packbf(a.z, a.w);
  o.z = packbf(b.x, b.y); o.w = packbf(b.z, b.w);
  ((uint4*)xb)[i] = o;
}

__global__ void prep_w_kernel(const float* __restrict__ qkv_w, const float* __restrict__ proj_w,
                              unsigned short* __restrict__ wqkvT, unsigned short* __restrict__ wprojT) {
  int tid = blockIdx.x * 256 + threadIdx.x;
  if (tid < QKVN * DIMC) {
    int n = tid / DIMC, k = tid - n * DIMC;
    wqkvT[tid] = bf16rne(qkv_w[(size_t)k * QKVN + n]);
  }
  if (tid < DIMC * DIMC) {
    int n = tid / DIMC, k = tid - n * DIMC;
    wprojT[tid] = bf16rne(proj_w[(size_t)k * DIMC + n]);
  }
}

// Transposed, jt-PAIRED bias (f32, pre * log2e, pad -> -1e30) — R6-verified layout:
// biasT[h][it][jp][q][l15][e], e in 0..7: jt = 2*jp + (e>>2), r = e&3,
// value = bias_table[rel_idx[min(it*16+l15,342)][jt*16+4q+r]][h] * log2e.
__global__ void prep_biasT_kernel(const float* __restrict__ bias_table, const int* __restrict__ rel_idx,
                                  float* __restrict__ biasT) {
  int tid = blockIdx.x * 256 + threadIdx.x;
  if (tid >= NHEAD * 22 * 11 * 64) return;
  int l15 = tid & 15;
  int q   = (tid >> 4) & 3;
  int rest = tid >> 6;            // (h*22 + it)*11 + jp
  int jp  = rest % 11;
  int it  = (rest / 11) % 22;
  int h   = rest / (11 * 22);
  int i = it * 16 + l15; if (i > NTOK - 1) i = NTOK - 1;
  const float LOG2E = 1.44269504088896340f;
  float o[8];
  #pragma unroll
  for (int e = 0; e < 8; e++) {
    int jt = 2 * jp + (e >> 2), r = e & 3;
    int j = jt * 16 + 4 * q + r;
    if (j < NTOK) {
      int idx = rel_idx[i * NTOK + j];
      o[e] = bias_table[idx * NHEAD + h] * LOG2E;
    } else {
      o[e] = -1e30f;
    }
  }
  float4* dst = (float4*)(biasT + (size_t)tid * 8);
  dst[0] = make_float4(o[0], o[1], o[2], o[3]);
  dst[1] = make_float4(o[4], o[5], o[6], o[7]);
}

// ---------------- GEMM (A[M][K] bf16, Bt[N][K] bf16, +bias) ----------------
// OUT_MODE 0: f32 row-major [M][Nn].  OUT_MODE 1: bf16 head-major q/k/v[h][m][32],
//             with the q third (which==0) pre-scaled by scale*log2e for the attn kernel.
// NBX = n-blocks per m-panel. 1-D grid, XCD panel-clustered: all NBX n-blocks of an
// m-panel map to the same XCD (bx&7) so the 96KB A-panel is L2-resident and reused NBX x.
// Grid must be 8 * ceil(686/8) * NBX = 8*86*NBX; surplus slots early-return.

typedef const __attribute__((address_space(1))) unsigned int* gas_t;
typedef __attribute__((address_space(3))) unsigned int* las_t;

__device__ __forceinline__ void load16_lds(const void* g, void* l) {
  __builtin_amdgcn_global_load_lds((gas_t)g, (las_t)l, 16, 0, 0);
}

template<int OUT_MODE, int NBX>
__global__ __launch_bounds__(256, 3) void gemm_bt_kernel(
    const unsigned short* __restrict__ A, const unsigned short* __restrict__ Bt,
    const float* __restrict__ bias, void* __restrict__ outp,
    int M, int Nn, int K)
{
  __shared__ __attribute__((aligned(16))) unsigned short Atile[128 * 64];
  __shared__ __attribute__((aligned(16))) unsigned short Btile[128 * 64];

  // XCD panel-clustering (bijective: panels [0..nby) split contiguously across 8 XCDs)
  const int bxx = blockIdx.x;
  const int xcd = bxx & 7;
  const int ii  = bxx >> 3;
  const int nby = M >> 7;                      // 686 m-panels
  const int qf = nby >> 3, rf = nby & 7;       // 85, 6
  const int cnt = qf + (xcd < rf ? 1 : 0);
  if (ii >= cnt * NBX) return;
  const int mbase = xcd * qf + (xcd < rf ? xcd : rf);
  const int mpan  = mbase + ii / NBX;
  const int npan  = ii - (ii / NBX) * NBX;
  const int m0 = mpan * 128, n0 = npan * 128;

  const int t = threadIdx.x;
  const int lane = t & 63, w = t >> 6;
  const int q = lane >> 4, l15 = lane & 15;
  const int wm = w >> 1, wn = w & 1;

  f32x4 acc[4][4] = {};

  for (int kk = 0; kk < K; kk += 64) {
    #pragma unroll
    for (int i = 0; i < 4; i++) {
      int chunk = i * 256 + t;
      int r = chunk >> 3, cl = chunk & 7;
      int cg = cl ^ (r & 7);
      load16_lds(A + (size_t)(m0 + r) * K + kk + cg * 8, Atile + chunk * 8);
      load16_lds(Bt + (size_t)(n0 + r) * K + kk + cg * 8, Btile + chunk * 8);
    }
    __syncthreads();
    const bf16x8* As = (const bf16x8*)Atile;
    const bf16x8* Bs = (const bf16x8*)Btile;
    #pragma unroll
    for (int kq = 0; kq < 2; kq++) {
      bf16x8 af[4], bfr[4];
      #pragma unroll
      for (int mt = 0; mt < 4; mt++) {
        int m = wm * 64 + mt * 16 + l15;
        af[mt] = As[m * 8 + ((kq * 4 + q) ^ (m & 7))];
      }
      #pragma unroll
      for (int nt = 0; nt < 4; nt++) {
        int nr = wn * 64 + nt * 16 + l15;
        bfr[nt] = Bs[nr * 8 + ((kq * 4 + q) ^ (nr & 7))];
      }
      #pragma unroll
      for (int mt = 0; mt < 4; mt++)
        #pragma unroll
        for (int nt = 0; nt < 4; nt++)
          acc[mt][nt] = __builtin_amdgcn_mfma_f32_16x16x32_bf16(af[mt], bfr[nt], acc[mt][nt], 0, 0, 0);
    }
    __syncthreads();
  }

  const float QSC = 0.17677669529663689f * 1.44269504088896340f;  // scale * log2e
  #pragma unroll
  for (int nt = 0; nt < 4; nt++) {
    int nn = n0 + wn * 64 + nt * 16;      // multiple of 16
    float bv = bias[nn + l15];
    #pragma unroll
    for (int mt = 0; mt < 4; mt++) {
      int mb = m0 + wm * 64 + mt * 16 + q * 4;
      #pragma unroll
      for (int r = 0; r < 4; r++) {
        float v = acc[mt][nt][r] + bv;
        if (OUT_MODE == 0) {
          ((float*)outp)[(size_t)(mb + r) * Nn + nn + l15] = v;
        } else {
          int which = nn / DIMC;
          if (which == 0) v *= QSC;   // pre-scale q so attn does s+b (no fma, no CS)
          int hh = (nn - which * DIMC) >> 5;
          int d0 = nn & 16;
          size_t off = ((size_t)(which * NHEAD + hh) * M_TOT + (mb + r)) * 32 + d0 + l15;
          ((unsigned short*)outp)[off] = bf16rne(v);
        }
      }
    }
  }
}

// ---------------- attention: one block (512 threads) per (b,h) ----------------

#define VST 362  // V^T LDS row stride (elements)

__global__ __launch_bounds__(512, 4) void attn_kernel(
    const unsigned short* __restrict__ qhead,  // [3][12][M_TOT][32] bf16 (q pre-scaled)
    const float* __restrict__ biasT,           // [12][22][11][4][16][8] f32 (pre * log2e)
    unsigned short* __restrict__ attnout)      // [M_TOT][384] bf16
{
  __shared__ __attribute__((aligned(16))) unsigned short Klds[22 * 512]; // fragment-packed
  __shared__ __attribute__((aligned(16))) unsigned short Vt[32 * VST];   // V^T[d][j]
  const int bx = blockIdx.x;
  // XCD head-clustering: blockIdx round-robins over 8 XCDs (bx&7 ~ XCD); give each XCD
  // whole heads so its L2 holds 1-2 bias slabs instead of all 12.
  const int g = bx & 7, s = bx >> 3;            // s in 0..383
  int h, b;
  if (s < 256) { h = g; b = s; }
  else { int j = g * 128 + (s - 256); h = 8 + (j >> 8); b = j & 255; }

  const int t = threadIdx.x;
  const int lane = t & 63, w = t >> 6;     // w in 0..7
  const int q = lane >> 4, l15 = lane & 15;

  const unsigned short* Qslab = qhead + ((size_t)(0 * NHEAD + h) * M_TOT + (size_t)b * NTOK) * 32;
  const unsigned short* Kslab = qhead + ((size_t)(1 * NHEAD + h) * M_TOT + (size_t)b * NTOK) * 32;
  const unsigned short* Vslab = qhead + ((size_t)(2 * NHEAD + h) * M_TOT + (size_t)b * NTOK) * 32;

  // stage K fragment-packed: Klds[jt*512 + lane*8] = K[jt*16 + l15][q*8..]
  for (int jt = w; jt < 22; jt += 8)
    load16_lds(Kslab + (size_t)(jt * 16 + l15) * 32 + q * 8, Klds + jt * 512 + lane * 8);
  // jt=21 rows 343..351 read past the slab into adjacent slab data: finite bf16, masked by bias pad.

  // stage V^T with conflict-free writes
  for (int j = t; j < NTOK; j += 512) {
    #pragma unroll
    for (int c = 0; c < 4; c++) {
      uint4 vd = *(const uint4*)(Vslab + (size_t)j * 32 + c * 8);
      const unsigned short* vs = (const unsigned short*)&vd;
      #pragma unroll
      for (int u = 0; u < 8; u++)
        Vt[(c * 8 + u) * VST + j] = vs[u];
    }
  }
  // zero V^T pad columns j in [343,359) so p=0 * garbage can't make NaN
  for (int idx = t; idx < 32 * 16; idx += 512)
    Vt[(idx >> 4) * VST + NTOK + (idx & 15)] = 0;
  __syncthreads();

  // ones fragment for the den-MFMA (B-operand all 1.0bf16): D[i][j] = sum_k P[i][k]
  union { unsigned u[2]; bf16x4 v; } ones_u;
  ones_u.u[0] = 0x3F803F80u; ones_u.u[1] = 0x3F803F80u;
  const bf16x4 ones4 = ones_u.v;

  // each wave: 32 query rows (two 16-row tiles A,B) per iteration; 11 pairs over 8 waves
  for (int pr = w; pr < 11; pr += 8) {
    int i0 = pr * 32;
    int iqA = i0 + l15;      iqA = iqA > (NTOK - 1) ? (NTOK - 1) : iqA;
    int iqB = i0 + 16 + l15; iqB = iqB > (NTOK - 1) ? (NTOK - 1) : iqB;
    bf16x8 bqA = *(const bf16x8*)(Qslab + (size_t)iqA * 32 + q * 8);
    bf16x8 bqB = *(const bf16x8*)(Qslab + (size_t)iqB * 32 + q * 8);

    // bias stream bases for row tiles it=2pr (A) / 2pr+1 (B); 2KB (2 f32x4/lane) per jt-pair
    const float* bApt = biasT + ((size_t)(h * 22 + pr * 2) * 11) * 512 + q * 128 + l15 * 8;
    const float* bBpt = bApt + 11 * 512;

    f32x4 oA0 = {0.f,0.f,0.f,0.f}, oA1 = {0.f,0.f,0.f,0.f};
    f32x4 oB0 = {0.f,0.f,0.f,0.f}, oB1 = {0.f,0.f,0.f,0.f};
    f32x4 denA4 = {0.f,0.f,0.f,0.f}, denB4 = {0.f,0.f,0.f,0.f};

    // one jt step: QK -> (s+b) -> exp2 -> bf16 cast pack -> den/PV MFMAs (setprio'd)
    auto jt_step = [&](int jt, f32x4 cbA, f32x4 cbB) {
      bf16x8 ak = *(const bf16x8*)(Klds + jt * 512 + lane * 8);  // ds_read_b128, stride-1
      f32x4 z = {0.f,0.f,0.f,0.f};
      f32x4 sA = __builtin_amdgcn_mfma_f32_16x16x32_bf16(ak, bqA, z, 0, 0, 0);
      f32x4 sB = __builtin_amdgcn_mfma_f32_16x16x32_bf16(ak, bqB, z, 0, 0, 0);
      f32x4 psA = sA + cbA;   // v_pk_add_f32 pairs (q pre-scaled by scale*log2e)
      f32x4 psB = sB + cbB;
      float pA0 = __builtin_amdgcn_exp2f(psA[0]);
      float pA1 = __builtin_amdgcn_exp2f(psA[1]);
      float pA2 = __builtin_amdgcn_exp2f(psA[2]);
      float pA3 = __builtin_amdgcn_exp2f(psA[3]);
      float pB0 = __builtin_amdgcn_exp2f(psB[0]);
      float pB1 = __builtin_amdgcn_exp2f(psB[1]);
      float pB2 = __builtin_amdgcn_exp2f(psB[2]);
      float pB3 = __builtin_amdgcn_exp2f(psB[3]);
      bf16x4 pfA = { (__bf16)pA0, (__bf16)pA1, (__bf16)pA2, (__bf16)pA3 };  // v_cvt_pk_bf16_f32
      bf16x4 pfB = { (__bf16)pB0, (__bf16)pB1, (__bf16)pB2, (__bf16)pB3 };
      bf16x4 vf0 = *(const bf16x4*)(Vt + l15 * VST + jt * 16 + 4 * q);
      bf16x4 vf1 = *(const bf16x4*)(Vt + (16 + l15) * VST + jt * 16 + 4 * q);
      __builtin_amdgcn_s_setprio(1);   // favor this wave while its MFMA cluster issues
      denA4 = __builtin_amdgcn_mfma_f32_16x16x16bf16_1k(pfA, ones4, denA4, 0, 0, 0);
      denB4 = __builtin_amdgcn_mfma_f32_16x16x16bf16_1k(pfB, ones4, denB4, 0, 0, 0);
      oA0 = __builtin_amdgcn_mfma_f32_16x16x16bf16_1k(pfA, vf0, oA0, 0, 0, 0);
      oA1 = __builtin_amdgcn_mfma_f32_16x16x16bf16_1k(pfA, vf1, oA1, 0, 0, 0);
      oB0 = __builtin_amdgcn_mfma_f32_16x16x16bf16_1k(pfB, vf0, oB0, 0, 0, 0);
      oB1 = __builtin_amdgcn_mfma_f32_16x16x16bf16_1k(pfB, vf1, oB1, 0, 0, 0);
      __builtin_amdgcn_s_setprio(0);
    };

    // explicit named double-buffer over 11 jt-pair chunks (NO dynamic register indexing):
    // consume chunk c, then issue load of chunk c+2 -> ~2 jt of compute covers L2 latency.
    // unroll 1: keep the loop rolled so the scheduler can't hoist all chunk loads (R6 spill).
    f32x4 bXA0 = *(const f32x4*)(bApt);
    f32x4 bXA1 = *(const f32x4*)(bApt + 4);
    f32x4 bXB0 = *(const f32x4*)(bBpt);
    f32x4 bXB1 = *(const f32x4*)(bBpt + 4);
    f32x4 bYA0 = *(const f32x4*)(bApt + 512);
    f32x4 bYA1 = *(const f32x4*)(bApt + 516);
    f32x4 bYB0 = *(const f32x4*)(bBpt + 512);
    f32x4 bYB1 = *(const f32x4*)(bBpt + 516);

    #pragma unroll 1
    for (int jp = 0; jp < 10; jp += 2) {
      jt_step(2 * jp,     bXA0, bXB0);
      jt_step(2 * jp + 1, bXA1, bXB1);
      bXA0 = *(const f32x4*)(bApt + (jp + 2) * 512);       // jp+2 <= 10 always
      bXA1 = *(const f32x4*)(bApt + (jp + 2) * 512 + 4);
      bXB0 = *(const f32x4*)(bBpt + (jp + 2) * 512);
      bXB1 = *(const f32x4*)(bBpt + (jp + 2) * 512 + 4);
      jt_step(2 * jp + 2, bYA0, bYB0);
      jt_step(2 * jp + 3, bYA1, bYB1);
      int c3 = (jp + 3 > 10) ? 10 : (jp + 3);              // clamped dead load at jp=8
      bYA0 = *(const f32x4*)(bApt + c3 * 512);
      bYA1 = *(const f32x4*)(bApt + c3 * 512 + 4);
      bYB0 = *(const f32x4*)(bBpt + c3 * 512);
      bYB1 = *(const f32x4*)(bBpt + c3 * 512 + 4);
    }
    jt_step(20, bXA0, bXB0);
    jt_step(21, bXA1, bXB1);

    // denA4[r]/denB4[r] are row-aligned with oA*/oB*: row = i0 + 4q + r (A), +16 (B)
    #pragma unroll
    for (int r = 0; r < 4; r++) {
      int rr = 4 * q + r;
      int iA = i0 + rr, iB = i0 + 16 + rr;
      if (iA < NTOK) {
        float inv = __builtin_amdgcn_rcpf(denA4[r]);
        size_t orow = ((size_t)b * NTOK + iA) * DIMC + h * 32;
        attnout[orow + l15]      = bf16rne(oA0[r] * inv);
        attnout[orow + 16 + l15] = bf16rne(oA1[r] * inv);
      }
      if (iB < NTOK) {
        float inv = __builtin_amdgcn_rcpf(denB4[r]);
        size_t orow = ((size_t)b * NTOK + iB) * DIMC + h * 32;
        attnout[orow + l15]      = bf16rne(oB0[r] * inv);
        attnout[orow + 16 + l15] = bf16rne(oB1[r] * inv);
      }
    }
  }
}

// ---------------- launch ----------------

extern "C" void kernel_launch(void* const* d_in, const int* in_sizes, int n_in,
                              void* d_out, int out_size, void* d_ws, size_t ws_size,
                              hipStream_t stream) {
  const float* x          = (const float*)d_in[0];
  const float* qkv_w      = (const float*)d_in[1];
  const float* qkv_b      = (const float*)d_in[2];
  const float* proj_w     = (const float*)d_in[3];
  const float* proj_b     = (const float*)d_in[4];
  const float* bias_table = (const float*)d_in[5];
  const int*   rel_idx    = (const int*)d_in[6];

  char* p = (char*)d_ws;
  unsigned short* xb      = (unsigned short*)p; p += (size_t)M_TOT * DIMC * 2;      // 67.4 MB
  unsigned short* wqkvT   = (unsigned short*)p; p += (size_t)QKVN * DIMC * 2;       // 0.9 MB
  unsigned short* wprojT  = (unsigned short*)p; p += (size_t)DIMC * DIMC * 2;       // 0.3 MB
  float*          biasT   = (float*)p;          p += (size_t)NHEAD * TSLAB * 4;     // 5.9 MB
  unsigned short* qhead   = (unsigned short*)p; p += (size_t)3 * NHEAD * M_TOT * 32 * 2; // 202.3 MB
  unsigned short* attnout = (unsigned short*)p; p += (size_t)M_TOT * DIMC * 2;      // 67.4 MB

  cvt_x_kernel<<<(M_TOT * DIMC / 8 + 255) / 256, 256, 0, stream>>>(x, xb, M_TOT * DIMC / 8);
  prep_w_kernel<<<(QKVN * DIMC + 255) / 256, 256, 0, stream>>>(qkv_w, proj_w, wqkvT, wprojT);
  prep_biasT_kernel<<<(NHEAD * 22 * 11 * 64 + 255) / 256, 256, 0, stream>>>(bias_table, rel_idx, biasT);
  // grids: 8 XCD slots * ceil(686/8)=86 panel-slots * NBX n-blocks (surplus early-returns)
  gemm_bt_kernel<1, 9><<<8 * 86 * 9, 256, 0, stream>>>(
      xb, wqkvT, qkv_b, (void*)qhead, M_TOT, QKVN, DIMC);
  attn_kernel<<<BWIN * NHEAD, 512, 0, stream>>>(qhead, biasT, attnout);
  gemm_bt_kernel<0, 3><<<8 * 86 * 3, 256, 0, stream>>>(
      attnout, wprojT, proj_b, d_out, M_TOT, DIMC, DIMC);
}